// Round 2
// baseline (8472.791 us; speedup 1.0000x reference)
//
#include <hip/hip_runtime.h>
#include <math.h>

// Problem constants
#define NBATCH 16
#define CDIM   384
#define NPIX   4096      // H*W = 64*64
#define HDCH   96        // channels per head
#define NROWS  65536     // NBATCH*NPIX

typedef unsigned short bf16;

__device__ __forceinline__ float b2f(bf16 u) {
    union { unsigned int i; float f; } c; c.i = ((unsigned int)u) << 16; return c.f;
}
__device__ __forceinline__ bf16 f2b(float f) {
    union { float f; unsigned int i; } c; c.f = f;
    unsigned int r = (c.i + 0x7FFFu + ((c.i >> 16) & 1u)) >> 16;
    return (bf16)r;
}

// ---------------------------------------------------------------------------
// 0) zero the knormsq accumulators (30720 floats)
// ---------------------------------------------------------------------------
__global__ __launch_bounds__(256) void zero_kernel(float* __restrict__ p) {
    p[blockIdx.x * 256 + threadIdx.x] = 0.0f;
}

// ---------------------------------------------------------------------------
// 1) Fourier positional embedding: pos[n, c] (bf16 out)
// ---------------------------------------------------------------------------
__global__ __launch_bounds__(128) void pos_kernel(const float* __restrict__ pos_w,
                                                  const float* __restrict__ pos_b,
                                                  bf16* __restrict__ pos) {
    __shared__ float feat[64];
    int n = blockIdx.x;
    int yi = n >> 6, xi = n & 63;
    int tid = threadIdx.x;
    if (tid < 64) {
        int j = tid & 31;
        int isx = tid >= 32;
        float base = (float)((isx ? xi : yi) + 1);
        float val = base / (64.0f + 1e-6f) * 6.283185307179586f;
        float e = (float)(2 * (j >> 1)) / 32.0f;
        float dt = powf(10000.0f, e);
        float a = val / dt;
        feat[isx * 32 + j] = (j & 1) ? cosf(a) : sinf(a);
    }
    __syncthreads();
    for (int c = tid; c < CDIM; c += 128) {
        float s = pos_b[c];
        const float* wr = pos_w + c * 64;
        #pragma unroll 16
        for (int j = 0; j < 64; ++j) s += feat[j] * wr[j];
        pos[n * CDIM + c] = f2b(s);
    }
}

// ---------------------------------------------------------------------------
// 2) Depthwise 3x3 conv (pad 1). xin fp32 chunk (+ prev bf16 chunk), out bf16.
// ---------------------------------------------------------------------------
__global__ __launch_bounds__(256) void dwconv_kernel(const float* __restrict__ xin, int in_ch0,
                                                     const bf16* __restrict__ prev, int prev_ch0,
                                                     const float* __restrict__ w,
                                                     const float* __restrict__ bias,
                                                     bf16* __restrict__ out, int out_ch0) {
    __shared__ float tile[66][66];
    int b = blockIdx.x / 96, c = blockIdx.x % 96;
    const float* ip = xin + (b * CDIM + in_ch0 + c) * NPIX;
    const bf16* pp = prev ? prev + (b * CDIM + prev_ch0 + c) * NPIX : nullptr;
    int tid = threadIdx.x;
    for (int i = tid; i < 66 * 66; i += 256) {
        int yy = i / 66 - 1, xx = i % 66 - 1;
        float v = 0.0f;
        if (yy >= 0 && yy < 64 && xx >= 0 && xx < 64) {
            v = ip[yy * 64 + xx];
            if (pp) v += b2f(pp[yy * 64 + xx]);
        }
        tile[i / 66][i % 66] = v;
    }
    __syncthreads();
    float wc[9];
    #pragma unroll
    for (int j = 0; j < 9; ++j) wc[j] = w[c * 9 + j];
    float b0 = bias[c];
    bf16* op = out + (b * CDIM + out_ch0 + c) * NPIX;
    for (int p = tid; p < NPIX; p += 256) {
        int y = p >> 6, x = p & 63;
        float a = b0;
        #pragma unroll
        for (int dy = 0; dy < 3; ++dy)
            #pragma unroll
            for (int dx = 0; dx < 3; ++dx)
                a += tile[y + dy][x + dx] * wc[dy * 3 + dx];
        op[p] = f2b(a);
    }
}

// convert channels [288:384) of x (fp32) into xcat (bf16)
__global__ __launch_bounds__(256) void convert_last_kernel(const float* __restrict__ x,
                                                           bf16* __restrict__ xcat) {
    int idx = blockIdx.x * 256 + threadIdx.x;   // 16*96*4096/4 = 1,572,864 threads
    int b = idx / (96 * 1024);
    int rem = idx % (96 * 1024);
    const float4* src = (const float4*)(x + (b * CDIM + 288) * NPIX);
    float4 v = src[rem];
    ushort4 o;
    o.x = f2b(v.x); o.y = f2b(v.y); o.z = f2b(v.z); o.w = f2b(v.w);
    ((ushort4*)(xcat + (b * CDIM + 288) * NPIX))[rem] = o;
}

// ---------------------------------------------------------------------------
// 3) x3[b,n,c] = xcat[b,c,n] + pos[n,c]   (LDS 32x32 transpose, bf16 io)
// ---------------------------------------------------------------------------
__global__ void x3_kernel(const bf16* __restrict__ xcat, const bf16* __restrict__ pos,
                          bf16* __restrict__ x3) {
    __shared__ float t[32][33];
    int c0 = blockIdx.x * 32, n0 = blockIdx.y * 32, b = blockIdx.z;
    int tx = threadIdx.x, ty = threadIdx.y;
    #pragma unroll
    for (int k = 0; k < 4; ++k) {
        int cl = ty + k * 8;
        t[cl][tx] = b2f(xcat[(b * CDIM + c0 + cl) * NPIX + n0 + tx]);
    }
    __syncthreads();
    #pragma unroll
    for (int k = 0; k < 4; ++k) {
        int nl = ty + k * 8;
        x3[(b * NPIX + n0 + nl) * CDIM + c0 + tx] =
            f2b(t[tx][nl] + b2f(pos[(n0 + nl) * CDIM + c0 + tx]));
    }
}

// ---------------------------------------------------------------------------
// 4) Row LayerNorm over C=384, bf16 io. map=1: fold-remap source row.
// ---------------------------------------------------------------------------
__global__ __launch_bounds__(128) void ln_kernel(const bf16* __restrict__ in,
                                                 const float* __restrict__ w,
                                                 const float* __restrict__ b,
                                                 bf16* __restrict__ out, int map) {
    int r = blockIdx.x;
    int src = r;
    if (map == 1) {
        int bb = r >> 12;
        int p = r & 4095;
        int y = p >> 6, x = p & 63;
        int patch = ((y & 1) << 1) | (x & 1);
        int blk = ((y >> 1) << 5) | (x >> 1);
        src = ((bb << 2) + patch) * 1024 + blk;
    }
    const bf16* row = in + src * CDIM;
    int tid = threadIdx.x;
    float v[3];
    float s1 = 0.0f, s2 = 0.0f;
    #pragma unroll
    for (int i = 0; i < 3; ++i) {
        v[i] = b2f(row[tid + i * 128]);
        s1 += v[i];
        s2 += v[i] * v[i];
    }
    __shared__ float r1[128], r2[128];
    r1[tid] = s1; r2[tid] = s2;
    __syncthreads();
    for (int off = 64; off > 0; off >>= 1) {
        if (tid < off) { r1[tid] += r1[tid + off]; r2[tid] += r2[tid + off]; }
        __syncthreads();
    }
    float mean = r1[0] * (1.0f / 384.0f);
    float var = fmaxf(r2[0] * (1.0f / 384.0f) - mean * mean, 0.0f);
    float rstd = rsqrtf(var + 1e-6f);
    #pragma unroll
    for (int i = 0; i < 3; ++i) {
        int c = tid + i * 128;
        out[r * CDIM + c] = f2b((v[i] - mean) * rstd * w[c] + b[c]);
    }
}

// ---------------------------------------------------------------------------
// 5) GEMM: C[M,Nout] = epi(A[M,K](bf16) @ W[Nout,K]^T(fp32) + bias)
//    mode 0: plain   mode 1: exact GELU   mode 2: res(bf16) + scalevec[c]*(.)
// ---------------------------------------------------------------------------
__global__ __launch_bounds__(256) void gemm_kernel(const bf16* __restrict__ A,
                                                   const float* __restrict__ W,
                                                   const float* __restrict__ bias,
                                                   bf16* __restrict__ C,
                                                   int M, int Nout, int K, int mode,
                                                   const bf16* __restrict__ res,
                                                   const float* __restrict__ scalevec) {
    __shared__ float As[16][68];
    __shared__ float Bs[16][68];
    int m0 = blockIdx.x * 64;
    int n0 = blockIdx.y * 64;
    int tid = threadIdx.x;
    int tx = tid & 15, ty = tid >> 4;
    int lRow = tid >> 2;
    int lK = (tid & 3) * 4;
    float acc[4][4] = {};
    for (int k0 = 0; k0 < K; k0 += 16) {
        ushort4 a4 = *(const ushort4*)(A + (size_t)(m0 + lRow) * K + k0 + lK);
        As[lK + 0][lRow] = b2f(a4.x); As[lK + 1][lRow] = b2f(a4.y);
        As[lK + 2][lRow] = b2f(a4.z); As[lK + 3][lRow] = b2f(a4.w);
        float4 b4 = *(const float4*)(W + (size_t)(n0 + lRow) * K + k0 + lK);
        Bs[lK + 0][lRow] = b4.x; Bs[lK + 1][lRow] = b4.y;
        Bs[lK + 2][lRow] = b4.z; Bs[lK + 3][lRow] = b4.w;
        __syncthreads();
        #pragma unroll
        for (int k = 0; k < 16; ++k) {
            float ar[4], br[4];
            #pragma unroll
            for (int i = 0; i < 4; ++i) ar[i] = As[k][ty * 4 + i];
            #pragma unroll
            for (int j = 0; j < 4; ++j) br[j] = Bs[k][tx * 4 + j];
            #pragma unroll
            for (int i = 0; i < 4; ++i)
                #pragma unroll
                for (int j = 0; j < 4; ++j)
                    acc[i][j] += ar[i] * br[j];
        }
        __syncthreads();
    }
    #pragma unroll
    for (int i = 0; i < 4; ++i) {
        int row = m0 + ty * 4 + i;
        #pragma unroll
        for (int j = 0; j < 4; ++j) {
            int col = n0 + tx * 4 + j;
            float v = acc[i][j] + bias[col];
            if (mode == 1) {
                v = 0.5f * v * (1.0f + erff(v * 0.70710678118654752f));
            } else if (mode == 2) {
                v = b2f(res[(size_t)row * Nout + col]) + scalevec[col] * v;
            }
            C[(size_t)row * Nout + col] = f2b(v);
        }
    }
}

// ---------------------------------------------------------------------------
// 6) k column sum-of-squares (over tokens), atomic partials. kv bf16 [rows,768].
// ---------------------------------------------------------------------------
__global__ __launch_bounds__(384) void knormsq_kernel(const bf16* __restrict__ kv,
                                                      float* __restrict__ outk,
                                                      int n_len, int chunk) {
    int bi = blockIdx.x;
    int n0 = blockIdx.y * chunk;
    int ch = threadIdx.x;
    const bf16* base = kv + (size_t)(bi * n_len + n0) * 768 + ch;
    float s = 0.0f;
    for (int t = 0; t < chunk; ++t) {
        float v = b2f(base[(size_t)t * 768]);
        s += v * v;
    }
    atomicAdd(&outk[bi * CDIM + ch], s);
}

// ---------------------------------------------------------------------------
// 7) Fused channel attention (XCA mode 0 / window-attn mode 1).
//    q: mode0 fp32 (qf), mode1 bf16 (qb); kv bf16. Out bf16.
// ---------------------------------------------------------------------------
__global__ __launch_bounds__(256) void chan_attn_kernel(const float* __restrict__ qf,
                                                        const bf16* __restrict__ qb,
                                                        const bf16* __restrict__ kv,
                                                        const float* __restrict__ knormsq,
                                                        const float* __restrict__ temp,
                                                        bf16* __restrict__ out,
                                                        int n_len, int mode) {
    __shared__ float S[96][97];
    __shared__ float Qt[96][33];
    __shared__ float KVt[96][33];
    __shared__ float knrm[96];
    int tid = threadIdx.x;
    int bi = blockIdx.x >> 2, h = blockIdx.x & 3;
    int koff = h * HDCH;
    const size_t qoff = (size_t)(bi * CDIM + koff) * n_len;
    const bf16* kvb = kv + (size_t)bi * n_len * 768;
    if (tid < 96) knrm[tid] = 1.0f / fmaxf(sqrtf(knormsq[bi * CDIM + koff + tid]), 1e-12f);
    __syncthreads();

    int tx = tid & 15, ty = tid >> 4;
    float acc[6][6] = {};
    for (int n0 = 0; n0 < n_len; n0 += 32) {
        for (int i = tid; i < 96 * 32; i += 256) {
            int c = i >> 5, t = i & 31;
            Qt[c][t] = (mode == 0) ? qf[qoff + (size_t)c * n_len + n0 + t]
                                   : b2f(qb[qoff + (size_t)c * n_len + n0 + t]);
        }
        for (int i = tid; i < 96 * 32; i += 256) {
            int d = i % 96, t = i / 96;
            KVt[d][t] = b2f(kvb[(size_t)(n0 + t) * 768 + koff + d]) * knrm[d];
        }
        __syncthreads();
        #pragma unroll 4
        for (int t = 0; t < 32; ++t) {
            float qr[6], kr[6];
            #pragma unroll
            for (int u = 0; u < 6; ++u) { qr[u] = Qt[ty * 6 + u][t]; kr[u] = KVt[tx * 6 + u][t]; }
            #pragma unroll
            for (int u = 0; u < 6; ++u)
                #pragma unroll
                for (int v = 0; v < 6; ++v)
                    acc[u][v] += qr[u] * kr[v];
        }
        __syncthreads();
    }
    float tv = (mode == 0) ? temp[h] : 1.0f;
    #pragma unroll
    for (int u = 0; u < 6; ++u)
        #pragma unroll
        for (int v = 0; v < 6; ++v)
            S[ty * 6 + u][tx * 6 + v] = acc[u][v] * tv;
    __syncthreads();

    if (tid < 96) {
        float* Sr = S[tid];
        if (mode == 0) {
            float m = -1e30f;
            for (int d = 0; d < 96; ++d) m = fmaxf(m, Sr[d]);
            float s = 0.0f;
            for (int d = 0; d < 96; ++d) s += expf(Sr[d] - m);
            float inv = 1.0f / s;
            for (int d = 0; d < 96; ++d) Sr[d] = expf(Sr[d] - m) * inv;
        } else {
            const float RSQ = 0.10206207261596575f;  // 1/sqrt(96)
            float m1 = -1e30f;
            for (int d = 0; d < 96; ++d) m1 = fmaxf(m1, Sr[d]);
            float s1 = 0.0f;
            for (int d = 0; d < 96; ++d) s1 += expf(Sr[d] - m1);
            float inv1 = 1.0f / s1;
            float m2 = -1e30f;
            for (int d = 0; d < 96; ++d) {
                float a = 0.5f * Sr[d] * RSQ + 0.5f * expf(Sr[d] - m1) * inv1;
                m2 = fmaxf(m2, a);
            }
            float s2 = 0.0f;
            for (int d = 0; d < 96; ++d) {
                float a = 0.5f * Sr[d] * RSQ + 0.5f * expf(Sr[d] - m1) * inv1;
                s2 += expf(a - m2);
            }
            float inv2 = 1.0f / s2;
            for (int d = 0; d < 96; ++d) {
                float a = 0.5f * Sr[d] * RSQ + 0.5f * expf(Sr[d] - m1) * inv1;
                Sr[d] = expf(a - m2) * inv2;
            }
        }
    }
    __syncthreads();

    int tn = tid & 31, tc = tid >> 5;
    for (int n0 = 0; n0 < n_len; n0 += 32) {
        for (int i = tid; i < 96 * 32; i += 256) {
            int d = i % 96, t = i / 96;
            KVt[d][t] = b2f(kvb[(size_t)(n0 + t) * 768 + 384 + koff + d]);
        }
        __syncthreads();
        #pragma unroll
        for (int j = 0; j < 12; ++j) {
            int c = tc * 12 + j;
            float a = 0.0f;
            #pragma unroll 8
            for (int d = 0; d < 96; ++d) a += S[c][d] * KVt[d][tn];
            if (mode == 0)
                out[(size_t)(bi * n_len + n0 + tn) * CDIM + koff + c] = f2b(a);
            else
                out[(size_t)((h * 64 + bi) * HDCH + c) * n_len + n0 + tn] = f2b(a);
        }
        __syncthreads();
    }
}

// ---------------------------------------------------------------------------
// 8) Unfold gathers
// cu_t[b2, ch, blk] = inp[b, ch, y, x]  (channel-major, bf16)
// ---------------------------------------------------------------------------
__global__ __launch_bounds__(256) void unfold_cu_kernel(const float* __restrict__ xin,
                                                        bf16* __restrict__ cu) {
    int idx = blockIdx.x * 256 + threadIdx.x;    // 64*384*1024 total
    int b2 = idx / (CDIM * 1024);
    int rem = idx % (CDIM * 1024);
    int ch = rem >> 10, blk = rem & 1023;
    int b = b2 >> 2, patch = b2 & 3;
    int y = ((blk >> 5) << 1) | (patch >> 1);
    int x = ((blk & 31) << 1) | (patch & 1);
    cu[idx] = f2b(xin[(size_t)(b * CDIM + ch) * NPIX + (y << 6) + x]);
}

// xu[b2*1024+blk, ch] = conv_out(x4)[...] (row-major, bf16)
__global__ __launch_bounds__(256) void unfold_xu_kernel(const bf16* __restrict__ x4,
                                                        const float* __restrict__ cw,
                                                        const float* __restrict__ cb,
                                                        bf16* __restrict__ xu) {
    int idx = blockIdx.x * 256 + threadIdx.x;
    int row = idx / CDIM, ch = idx % CDIM;
    int b2 = row >> 10, blk = row & 1023;
    int b = b2 >> 2, patch = b2 & 3;
    int y = ((blk >> 5) << 1) | (patch >> 1);
    int x = ((blk & 31) << 1) | (patch & 1);
    xu[idx] = f2b(b2f(x4[(size_t)(b * NPIX + (y << 6) + x) * CDIM + ch]) * cw[ch] + cb[ch]);
}

// ---------------------------------------------------------------------------
// 9) out[b,c,p] = inp[b,c,p] + gamma[c] * final[(b*4096+p), c]  (fp32 out)
// ---------------------------------------------------------------------------
__global__ void out_kernel(const float* __restrict__ xin, const bf16* __restrict__ fin,
                           const float* __restrict__ gamma, float* __restrict__ outp) {
    __shared__ float t[32][33];
    int c0 = blockIdx.x * 32, p0 = blockIdx.y * 32, b = blockIdx.z;
    int tx = threadIdx.x, ty = threadIdx.y;
    #pragma unroll
    for (int k = 0; k < 4; ++k) {
        int pl = ty + k * 8;
        t[pl][tx] = b2f(fin[(size_t)(b * NPIX + p0 + pl) * CDIM + c0 + tx]);
    }
    __syncthreads();
    #pragma unroll
    for (int k = 0; k < 4; ++k) {
        int cl = ty + k * 8;
        size_t addr = (size_t)(b * CDIM + c0 + cl) * NPIX + p0 + tx;
        outp[addr] = xin[addr] + gamma[c0 + cl] * t[tx][cl];
    }
}

// ---------------------------------------------------------------------------
extern "C" void kernel_launch(void* const* d_in, const int* in_sizes, int n_in,
                              void* d_out, int out_size, void* d_ws, size_t ws_size,
                              hipStream_t stream) {
    (void)in_sizes; (void)n_in; (void)out_size; (void)ws_size;
    const float* x         = (const float*)d_in[0];
    const float* convs_w   = (const float*)d_in[1];
    const float* convs_b   = (const float*)d_in[2];
    const float* pos_w     = (const float*)d_in[3];
    const float* pos_b     = (const float*)d_in[4];
    const float* ln_xca_w  = (const float*)d_in[5];
    const float* ln_xca_b  = (const float*)d_in[6];
    const float* gamma_xca = (const float*)d_in[7];
    const float* xca_temp  = (const float*)d_in[8];
    const float* xca_kv_w  = (const float*)d_in[9];
    const float* xca_kv_b  = (const float*)d_in[10];
    const float* xca_proj_w= (const float*)d_in[11];
    const float* xca_proj_b= (const float*)d_in[12];
    const float* conv_out_w= (const float*)d_in[13];
    const float* conv_out_b= (const float*)d_in[14];
    const float* wa_kv_w   = (const float*)d_in[15];
    const float* wa_kv_b   = (const float*)d_in[16];
    const float* wa_proj_w = (const float*)d_in[17];
    const float* wa_proj_b = (const float*)d_in[18];
    const float* ln_w      = (const float*)d_in[19];
    const float* ln_b      = (const float*)d_in[20];
    const float* pw1_w     = (const float*)d_in[21];
    const float* pw1_b     = (const float*)d_in[22];
    const float* pw2_w     = (const float*)d_in[23];
    const float* pw2_b     = (const float*)d_in[24];
    const float* gamma     = (const float*)d_in[25];
    float* out = (float*)d_out;

    // Workspace: bf16 pools + fp32 accumulators. Total 204,595,200 B (~195 MiB).
    bf16* pos = (bf16*)d_ws;                 // 1,572,864 elems
    bf16* P1  = pos + 1572864;               // 25,165,824 elems (50.3 MB)
    bf16* P2  = P1 + 25165824;               // 25,165,824 elems
    bf16* P3  = P2 + 25165824;               // 50,331,648 elems (100.7 MB)
    float* knsq    = (float*)(P3 + 50331648);// 6,144 (xca)
    float* knsq_wa = knsq + 6144;            // 24,576 (wa)

    zero_kernel<<<120, 256, 0, stream>>>(knsq);  // zeros both knsq regions

    // pos embedding
    pos_kernel<<<4096, 128, 0, stream>>>(pos_w, pos_b, pos);

    // multi-scale depthwise conv chain -> P1 (xcat)
    dwconv_kernel<<<NBATCH * 96, 256, 0, stream>>>(x,   0, nullptr, 0,  convs_w,        convs_b,       P1, 0);
    dwconv_kernel<<<NBATCH * 96, 256, 0, stream>>>(x,  96, P1,      0,  convs_w + 864,  convs_b + 96,  P1, 96);
    dwconv_kernel<<<NBATCH * 96, 256, 0, stream>>>(x, 192, P1,     96,  convs_w + 1728, convs_b + 192, P1, 192);
    convert_last_kernel<<<6144, 256, 0, stream>>>(x, P1);

    // x3 = transpose(xcat) + pos -> P2
    x3_kernel<<<dim3(12, 128, NBATCH), dim3(32, 8), 0, stream>>>(P1, pos, P2);

    // XCA: LN -> kv -> knorm -> attention -> proj(+res*gamma_xca) = x4
    ln_kernel<<<NROWS, 128, 0, stream>>>(P2, ln_xca_w, ln_xca_b, P1, 0);
    gemm_kernel<<<dim3(1024, 12), 256, 0, stream>>>(P1, xca_kv_w, xca_kv_b, P3,
                                                    NROWS, 768, 384, 0, nullptr, nullptr);
    knormsq_kernel<<<dim3(16, 16), 384, 0, stream>>>(P3, knsq, 4096, 256);
    chan_attn_kernel<<<64, 256, 0, stream>>>(x, nullptr, P3, knsq, xca_temp, P1, 4096, 0);
    gemm_kernel<<<dim3(1024, 6), 256, 0, stream>>>(P1, xca_proj_w, xca_proj_b, P3,
                                                   NROWS, 384, 384, 2, P2, gamma_xca);  // x4 -> P3 lo

    // window attention
    unfold_cu_kernel<<<98304, 256, 0, stream>>>(x, P2);                                 // cu_t
    unfold_xu_kernel<<<98304, 256, 0, stream>>>(P3, conv_out_w, conv_out_b, P1);        // xu
    gemm_kernel<<<dim3(1024, 12), 256, 0, stream>>>(P1, wa_kv_w, wa_kv_b, P3,
                                                    NROWS, 768, 384, 0, nullptr, nullptr);
    knormsq_kernel<<<dim3(64, 4), 384, 0, stream>>>(P3, knsq_wa, 1024, 256);
    chan_attn_kernel<<<256, 256, 0, stream>>>(nullptr, P2, P3, knsq_wa, nullptr, P1, 1024, 1); // Xpre
    gemm_kernel<<<dim3(1024, 6), 256, 0, stream>>>(P1, wa_proj_w, wa_proj_b, P2,
                                                   NROWS, 384, 384, 0, nullptr, nullptr);      // Y

    // MLP: LN(fold remap) -> pw1(gelu) -> pw2, chunked 4x16384 rows
    ln_kernel<<<NROWS, 128, 0, stream>>>(P2, ln_w, ln_b, P1, 1);
    for (int ch = 0; ch < 4; ++ch) {
        gemm_kernel<<<dim3(256, 24), 256, 0, stream>>>(P1 + (size_t)ch * 16384 * 384, pw1_w, pw1_b,
                                                       P3, 16384, 1536, 384, 1, nullptr, nullptr);
        gemm_kernel<<<dim3(256, 6), 256, 0, stream>>>(P3, pw2_w, pw2_b,
                                                      P2 + (size_t)ch * 16384 * 384, 16384, 384, 1536,
                                                      0, nullptr, nullptr);
    }

    // out = inp + gamma * final (transpose back to NCHW)
    out_kernel<<<dim3(12, 128, NBATCH), dim3(32, 8), 0, stream>>>(x, P2, gamma, out);
}

// Round 3
// 5138.718 us; speedup vs baseline: 1.6488x; 1.6488x over previous
//
#include <hip/hip_runtime.h>
#include <math.h>

// Problem constants
#define NBATCH 16
#define CDIM   384
#define NPIX   4096      // H*W = 64*64
#define HDCH   96        // channels per head
#define NROWS  65536     // NBATCH*NPIX

typedef unsigned short bf16;

__device__ __forceinline__ float b2f(bf16 u) {
    union { unsigned int i; float f; } c; c.i = ((unsigned int)u) << 16; return c.f;
}
__device__ __forceinline__ bf16 f2b(float f) {
    union { float f; unsigned int i; } c; c.f = f;
    unsigned int r = (c.i + 0x7FFFu + ((c.i >> 16) & 1u)) >> 16;
    return (bf16)r;
}

// ---------------------------------------------------------------------------
// 0) zero scratch accumulators (knsq + S buffers), count = grid*256 floats
// ---------------------------------------------------------------------------
__global__ __launch_bounds__(256) void zero_kernel(float* __restrict__ p) {
    p[blockIdx.x * 256 + threadIdx.x] = 0.0f;
}

// ---------------------------------------------------------------------------
// 1) Fourier positional embedding: pos[n, c] (bf16 out)
// ---------------------------------------------------------------------------
__global__ __launch_bounds__(128) void pos_kernel(const float* __restrict__ pos_w,
                                                  const float* __restrict__ pos_b,
                                                  bf16* __restrict__ pos) {
    __shared__ float feat[64];
    int n = blockIdx.x;
    int yi = n >> 6, xi = n & 63;
    int tid = threadIdx.x;
    if (tid < 64) {
        int j = tid & 31;
        int isx = tid >= 32;
        float base = (float)((isx ? xi : yi) + 1);
        float val = base / (64.0f + 1e-6f) * 6.283185307179586f;
        float e = (float)(2 * (j >> 1)) / 32.0f;
        float dt = powf(10000.0f, e);
        float a = val / dt;
        feat[isx * 32 + j] = (j & 1) ? cosf(a) : sinf(a);
    }
    __syncthreads();
    for (int c = tid; c < CDIM; c += 128) {
        float s = pos_b[c];
        const float* wr = pos_w + c * 64;
        #pragma unroll 16
        for (int j = 0; j < 64; ++j) s += feat[j] * wr[j];
        pos[n * CDIM + c] = f2b(s);
    }
}

// ---------------------------------------------------------------------------
// 2) Depthwise 3x3 conv (pad 1). xin fp32 chunk (+ prev bf16 chunk), out bf16.
// ---------------------------------------------------------------------------
__global__ __launch_bounds__(256) void dwconv_kernel(const float* __restrict__ xin, int in_ch0,
                                                     const bf16* __restrict__ prev, int prev_ch0,
                                                     const float* __restrict__ w,
                                                     const float* __restrict__ bias,
                                                     bf16* __restrict__ out, int out_ch0) {
    __shared__ float tile[66][66];
    int b = blockIdx.x / 96, c = blockIdx.x % 96;
    const float* ip = xin + (b * CDIM + in_ch0 + c) * NPIX;
    const bf16* pp = prev ? prev + (b * CDIM + prev_ch0 + c) * NPIX : nullptr;
    int tid = threadIdx.x;
    for (int i = tid; i < 66 * 66; i += 256) {
        int yy = i / 66 - 1, xx = i % 66 - 1;
        float v = 0.0f;
        if (yy >= 0 && yy < 64 && xx >= 0 && xx < 64) {
            v = ip[yy * 64 + xx];
            if (pp) v += b2f(pp[yy * 64 + xx]);
        }
        tile[i / 66][i % 66] = v;
    }
    __syncthreads();
    float wc[9];
    #pragma unroll
    for (int j = 0; j < 9; ++j) wc[j] = w[c * 9 + j];
    float b0 = bias[c];
    bf16* op = out + (b * CDIM + out_ch0 + c) * NPIX;
    for (int p = tid; p < NPIX; p += 256) {
        int y = p >> 6, x = p & 63;
        float a = b0;
        #pragma unroll
        for (int dy = 0; dy < 3; ++dy)
            #pragma unroll
            for (int dx = 0; dx < 3; ++dx)
                a += tile[y + dy][x + dx] * wc[dy * 3 + dx];
        op[p] = f2b(a);
    }
}

// convert channels [288:384) of x (fp32) into xcat (bf16)
__global__ __launch_bounds__(256) void convert_last_kernel(const float* __restrict__ x,
                                                           bf16* __restrict__ xcat) {
    int idx = blockIdx.x * 256 + threadIdx.x;   // 16*96*4096/4 = 1,572,864 threads
    int b = idx / (96 * 1024);
    int rem = idx % (96 * 1024);
    const float4* src = (const float4*)(x + (b * CDIM + 288) * NPIX);
    float4 v = src[rem];
    ushort4 o;
    o.x = f2b(v.x); o.y = f2b(v.y); o.z = f2b(v.z); o.w = f2b(v.w);
    ((ushort4*)(xcat + (b * CDIM + 288) * NPIX))[rem] = o;
}

// ---------------------------------------------------------------------------
// 3) x3[b,n,c] = xcat[b,c,n] + pos[n,c]   (LDS 32x32 transpose, bf16 io)
// ---------------------------------------------------------------------------
__global__ void x3_kernel(const bf16* __restrict__ xcat, const bf16* __restrict__ pos,
                          bf16* __restrict__ x3) {
    __shared__ float t[32][33];
    int c0 = blockIdx.x * 32, n0 = blockIdx.y * 32, b = blockIdx.z;
    int tx = threadIdx.x, ty = threadIdx.y;
    #pragma unroll
    for (int k = 0; k < 4; ++k) {
        int cl = ty + k * 8;
        t[cl][tx] = b2f(xcat[(b * CDIM + c0 + cl) * NPIX + n0 + tx]);
    }
    __syncthreads();
    #pragma unroll
    for (int k = 0; k < 4; ++k) {
        int nl = ty + k * 8;
        x3[(b * NPIX + n0 + nl) * CDIM + c0 + tx] =
            f2b(t[tx][nl] + b2f(pos[(n0 + nl) * CDIM + c0 + tx]));
    }
}

// ---------------------------------------------------------------------------
// 4) Row LayerNorm over C=384, bf16 io. map=1: fold-remap source row.
// ---------------------------------------------------------------------------
__global__ __launch_bounds__(128) void ln_kernel(const bf16* __restrict__ in,
                                                 const float* __restrict__ w,
                                                 const float* __restrict__ b,
                                                 bf16* __restrict__ out, int map) {
    int r = blockIdx.x;
    int src = r;
    if (map == 1) {
        int bb = r >> 12;
        int p = r & 4095;
        int y = p >> 6, x = p & 63;
        int patch = ((y & 1) << 1) | (x & 1);
        int blk = ((y >> 1) << 5) | (x >> 1);
        src = ((bb << 2) + patch) * 1024 + blk;
    }
    const bf16* row = in + src * CDIM;
    int tid = threadIdx.x;
    float v[3];
    float s1 = 0.0f, s2 = 0.0f;
    #pragma unroll
    for (int i = 0; i < 3; ++i) {
        v[i] = b2f(row[tid + i * 128]);
        s1 += v[i];
        s2 += v[i] * v[i];
    }
    __shared__ float r1[128], r2[128];
    r1[tid] = s1; r2[tid] = s2;
    __syncthreads();
    for (int off = 64; off > 0; off >>= 1) {
        if (tid < off) { r1[tid] += r1[tid + off]; r2[tid] += r2[tid + off]; }
        __syncthreads();
    }
    float mean = r1[0] * (1.0f / 384.0f);
    float var = fmaxf(r2[0] * (1.0f / 384.0f) - mean * mean, 0.0f);
    float rstd = rsqrtf(var + 1e-6f);
    #pragma unroll
    for (int i = 0; i < 3; ++i) {
        int c = tid + i * 128;
        out[r * CDIM + c] = f2b((v[i] - mean) * rstd * w[c] + b[c]);
    }
}

// ---------------------------------------------------------------------------
// 5) GEMM: C[M,Nout] = epi(A[M,K](bf16) @ W[Nout,K]^T(fp32) + bias)
//    mode 0: plain   mode 1: exact GELU   mode 2: res(bf16) + scalevec[c]*(.)
// ---------------------------------------------------------------------------
__global__ __launch_bounds__(256) void gemm_kernel(const bf16* __restrict__ A,
                                                   const float* __restrict__ W,
                                                   const float* __restrict__ bias,
                                                   bf16* __restrict__ C,
                                                   int M, int Nout, int K, int mode,
                                                   const bf16* __restrict__ res,
                                                   const float* __restrict__ scalevec) {
    __shared__ float As[16][68];
    __shared__ float Bs[16][68];
    int m0 = blockIdx.x * 64;
    int n0 = blockIdx.y * 64;
    int tid = threadIdx.x;
    int tx = tid & 15, ty = tid >> 4;
    int lRow = tid >> 2;
    int lK = (tid & 3) * 4;
    float acc[4][4] = {};
    for (int k0 = 0; k0 < K; k0 += 16) {
        ushort4 a4 = *(const ushort4*)(A + (size_t)(m0 + lRow) * K + k0 + lK);
        As[lK + 0][lRow] = b2f(a4.x); As[lK + 1][lRow] = b2f(a4.y);
        As[lK + 2][lRow] = b2f(a4.z); As[lK + 3][lRow] = b2f(a4.w);
        float4 b4 = *(const float4*)(W + (size_t)(n0 + lRow) * K + k0 + lK);
        Bs[lK + 0][lRow] = b4.x; Bs[lK + 1][lRow] = b4.y;
        Bs[lK + 2][lRow] = b4.z; Bs[lK + 3][lRow] = b4.w;
        __syncthreads();
        #pragma unroll
        for (int k = 0; k < 16; ++k) {
            float ar[4], br[4];
            #pragma unroll
            for (int i = 0; i < 4; ++i) ar[i] = As[k][ty * 4 + i];
            #pragma unroll
            for (int j = 0; j < 4; ++j) br[j] = Bs[k][tx * 4 + j];
            #pragma unroll
            for (int i = 0; i < 4; ++i)
                #pragma unroll
                for (int j = 0; j < 4; ++j)
                    acc[i][j] += ar[i] * br[j];
        }
        __syncthreads();
    }
    #pragma unroll
    for (int i = 0; i < 4; ++i) {
        int row = m0 + ty * 4 + i;
        #pragma unroll
        for (int j = 0; j < 4; ++j) {
            int col = n0 + tx * 4 + j;
            float v = acc[i][j] + bias[col];
            if (mode == 1) {
                v = 0.5f * v * (1.0f + erff(v * 0.70710678118654752f));
            } else if (mode == 2) {
                v = b2f(res[(size_t)row * Nout + col]) + scalevec[col] * v;
            }
            C[(size_t)row * Nout + col] = f2b(v);
        }
    }
}

// ---------------------------------------------------------------------------
// 6) k column sum-of-squares (over tokens), atomic partials. kv bf16 [rows,768].
// ---------------------------------------------------------------------------
__global__ __launch_bounds__(384) void knormsq_kernel(const bf16* __restrict__ kv,
                                                      float* __restrict__ outk,
                                                      int n_len, int chunk) {
    int bi = blockIdx.x;
    int n0 = blockIdx.y * chunk;
    int ch = threadIdx.x;
    const bf16* base = kv + (size_t)(bi * n_len + n0) * 768 + ch;
    float s = 0.0f;
    for (int t = 0; t < chunk; ++t) {
        float v = b2f(base[(size_t)t * 768]);
        s += v * v;
    }
    atomicAdd(&outk[bi * CDIM + ch], s);
}

// ---------------------------------------------------------------------------
// 7a) S partial accumulate: S[pair, c, d] += sum_{n in chunk} Q[c,n] * Khat[d,n]
//     grid = npairs * nchunks; pair = (bi*4 + h)
// ---------------------------------------------------------------------------
__global__ __launch_bounds__(256) void chan_qk_kernel(const float* __restrict__ qf,
                                                      const bf16* __restrict__ qb,
                                                      const bf16* __restrict__ kv,
                                                      const float* __restrict__ knormsq,
                                                      float* __restrict__ Sg,
                                                      int n_len, int nchunks, int mode) {
    __shared__ float Qt[96][33];
    __shared__ float KVt[96][33];
    __shared__ float knrm[96];
    int pair = blockIdx.x / nchunks, ck = blockIdx.x % nchunks;
    int bi = pair >> 2, h = pair & 3;
    int koff = h * HDCH;
    int chunk = n_len / nchunks;
    int nbeg = ck * chunk, nend = nbeg + chunk;
    const size_t qoff = (size_t)(bi * CDIM + koff) * n_len;
    const bf16* kvb = kv + (size_t)bi * n_len * 768;
    int tid = threadIdx.x;
    if (tid < 96) knrm[tid] = 1.0f / fmaxf(sqrtf(knormsq[bi * CDIM + koff + tid]), 1e-12f);
    __syncthreads();
    int tx = tid & 15, ty = tid >> 4;
    float acc[6][6] = {};
    for (int n0 = nbeg; n0 < nend; n0 += 32) {
        for (int i = tid; i < 96 * 32; i += 256) {
            int c = i >> 5, t = i & 31;
            Qt[c][t] = (mode == 0) ? qf[qoff + (size_t)c * n_len + n0 + t]
                                   : b2f(qb[qoff + (size_t)c * n_len + n0 + t]);
        }
        for (int i = tid; i < 96 * 32; i += 256) {
            int d = i % 96, t = i / 96;
            KVt[d][t] = b2f(kvb[(size_t)(n0 + t) * 768 + koff + d]) * knrm[d];
        }
        __syncthreads();
        #pragma unroll 4
        for (int t = 0; t < 32; ++t) {
            float qr[6], kr[6];
            #pragma unroll
            for (int u = 0; u < 6; ++u) { qr[u] = Qt[ty * 6 + u][t]; kr[u] = KVt[tx * 6 + u][t]; }
            #pragma unroll
            for (int u = 0; u < 6; ++u)
                #pragma unroll
                for (int v = 0; v < 6; ++v)
                    acc[u][v] += qr[u] * kr[v];
        }
        __syncthreads();
    }
    float* Sp = Sg + (size_t)pair * 9216;
    #pragma unroll
    for (int u = 0; u < 6; ++u)
        #pragma unroll
        for (int v = 0; v < 6; ++v)
            atomicAdd(&Sp[(ty * 6 + u) * 96 + tx * 6 + v], acc[u][v]);
}

// ---------------------------------------------------------------------------
// 7b) softmax rows of S. mode 0: softmax(S*temp[h]); mode 1: double softmax.
// ---------------------------------------------------------------------------
__global__ __launch_bounds__(128) void chan_softmax_kernel(float* __restrict__ Sg,
                                                           const float* __restrict__ temp,
                                                           int mode) {
    int pair = blockIdx.x;
    int tid = threadIdx.x;
    if (tid >= 96) return;
    float* Sr = Sg + (size_t)pair * 9216 + tid * 96;
    if (mode == 0) {
        float tv = temp[pair & 3];
        float m = -1e30f;
        for (int d = 0; d < 96; ++d) m = fmaxf(m, Sr[d] * tv);
        float s = 0.0f;
        for (int d = 0; d < 96; ++d) s += expf(Sr[d] * tv - m);
        float inv = 1.0f / s;
        for (int d = 0; d < 96; ++d) Sr[d] = expf(Sr[d] * tv - m) * inv;
    } else {
        const float RSQ = 0.10206207261596575f;  // 1/sqrt(96)
        float m1 = -1e30f;
        for (int d = 0; d < 96; ++d) m1 = fmaxf(m1, Sr[d]);
        float s1 = 0.0f;
        for (int d = 0; d < 96; ++d) s1 += expf(Sr[d] - m1);
        float inv1 = 1.0f / s1;
        float m2 = -1e30f;
        for (int d = 0; d < 96; ++d) {
            float a = 0.5f * Sr[d] * RSQ + 0.5f * expf(Sr[d] - m1) * inv1;
            m2 = fmaxf(m2, a);
        }
        float s2 = 0.0f;
        for (int d = 0; d < 96; ++d) {
            float a = 0.5f * Sr[d] * RSQ + 0.5f * expf(Sr[d] - m1) * inv1;
            s2 += expf(a - m2);
        }
        float inv2 = 1.0f / s2;
        for (int d = 0; d < 96; ++d) {
            float a = 0.5f * Sr[d] * RSQ + 0.5f * expf(Sr[d] - m1) * inv1;
            Sr[d] = expf(a - m2) * inv2;
        }
    }
}

// ---------------------------------------------------------------------------
// 7c) PV: out[c,n] = sum_d attn[c,d] * V[d,n], token-chunked.
// ---------------------------------------------------------------------------
__global__ __launch_bounds__(256) void chan_pv_kernel(const float* __restrict__ Sg,
                                                      const bf16* __restrict__ kv,
                                                      bf16* __restrict__ out,
                                                      int n_len, int nchunks, int mode) {
    __shared__ float Sl[96][97];
    __shared__ float Vt[96][33];
    int pair = blockIdx.x / nchunks, ck = blockIdx.x % nchunks;
    int bi = pair >> 2, h = pair & 3;
    int koff = h * HDCH;
    int chunk = n_len / nchunks;
    int nbeg = ck * chunk, nend = nbeg + chunk;
    const bf16* kvb = kv + (size_t)bi * n_len * 768;
    int tid = threadIdx.x;
    const float* Sp = Sg + (size_t)pair * 9216;
    for (int i = tid; i < 9216; i += 256) Sl[i / 96][i % 96] = Sp[i];
    __syncthreads();
    int tn = tid & 31, tc = tid >> 5;
    for (int n0 = nbeg; n0 < nend; n0 += 32) {
        for (int i = tid; i < 96 * 32; i += 256) {
            int d = i % 96, t = i / 96;
            Vt[d][t] = b2f(kvb[(size_t)(n0 + t) * 768 + 384 + koff + d]);
        }
        __syncthreads();
        #pragma unroll
        for (int j = 0; j < 12; ++j) {
            int c = tc * 12 + j;
            float a = 0.0f;
            #pragma unroll 8
            for (int d = 0; d < 96; ++d) a += Sl[c][d] * Vt[d][tn];
            if (mode == 0)
                out[(size_t)(bi * n_len + n0 + tn) * CDIM + koff + c] = f2b(a);
            else
                out[(size_t)((h * 64 + bi) * HDCH + c) * n_len + n0 + tn] = f2b(a);
        }
        __syncthreads();
    }
}

// ---------------------------------------------------------------------------
// 8) Unfold gathers
// ---------------------------------------------------------------------------
__global__ __launch_bounds__(256) void unfold_cu_kernel(const float* __restrict__ xin,
                                                        bf16* __restrict__ cu) {
    int idx = blockIdx.x * 256 + threadIdx.x;    // 64*384*1024 total
    int b2 = idx / (CDIM * 1024);
    int rem = idx % (CDIM * 1024);
    int ch = rem >> 10, blk = rem & 1023;
    int b = b2 >> 2, patch = b2 & 3;
    int y = ((blk >> 5) << 1) | (patch >> 1);
    int x = ((blk & 31) << 1) | (patch & 1);
    cu[idx] = f2b(xin[(size_t)(b * CDIM + ch) * NPIX + (y << 6) + x]);
}

__global__ __launch_bounds__(256) void unfold_xu_kernel(const bf16* __restrict__ x4,
                                                        const float* __restrict__ cw,
                                                        const float* __restrict__ cb,
                                                        bf16* __restrict__ xu) {
    int idx = blockIdx.x * 256 + threadIdx.x;
    int row = idx / CDIM, ch = idx % CDIM;
    int b2 = row >> 10, blk = row & 1023;
    int b = b2 >> 2, patch = b2 & 3;
    int y = ((blk >> 5) << 1) | (patch >> 1);
    int x = ((blk & 31) << 1) | (patch & 1);
    xu[idx] = f2b(b2f(x4[(size_t)(b * NPIX + (y << 6) + x) * CDIM + ch]) * cw[ch] + cb[ch]);
}

// ---------------------------------------------------------------------------
// 9) out[b,c,p] = inp[b,c,p] + gamma[c] * final[(b*4096+p), c]  (fp32 out)
// ---------------------------------------------------------------------------
__global__ void out_kernel(const float* __restrict__ xin, const bf16* __restrict__ fin,
                           const float* __restrict__ gamma, float* __restrict__ outp) {
    __shared__ float t[32][33];
    int c0 = blockIdx.x * 32, p0 = blockIdx.y * 32, b = blockIdx.z;
    int tx = threadIdx.x, ty = threadIdx.y;
    #pragma unroll
    for (int k = 0; k < 4; ++k) {
        int pl = ty + k * 8;
        t[pl][tx] = b2f(fin[(size_t)(b * NPIX + p0 + pl) * CDIM + c0 + tx]);
    }
    __syncthreads();
    #pragma unroll
    for (int k = 0; k < 4; ++k) {
        int cl = ty + k * 8;
        size_t addr = (size_t)(b * CDIM + c0 + cl) * NPIX + p0 + tx;
        outp[addr] = xin[addr] + gamma[c0 + cl] * t[tx][cl];
    }
}

// ---------------------------------------------------------------------------
extern "C" void kernel_launch(void* const* d_in, const int* in_sizes, int n_in,
                              void* d_out, int out_size, void* d_ws, size_t ws_size,
                              hipStream_t stream) {
    (void)in_sizes; (void)n_in; (void)out_size; (void)ws_size;
    const float* x         = (const float*)d_in[0];
    const float* convs_w   = (const float*)d_in[1];
    const float* convs_b   = (const float*)d_in[2];
    const float* pos_w     = (const float*)d_in[3];
    const float* pos_b     = (const float*)d_in[4];
    const float* ln_xca_w  = (const float*)d_in[5];
    const float* ln_xca_b  = (const float*)d_in[6];
    const float* gamma_xca = (const float*)d_in[7];
    const float* xca_temp  = (const float*)d_in[8];
    const float* xca_kv_w  = (const float*)d_in[9];
    const float* xca_kv_b  = (const float*)d_in[10];
    const float* xca_proj_w= (const float*)d_in[11];
    const float* xca_proj_b= (const float*)d_in[12];
    const float* conv_out_w= (const float*)d_in[13];
    const float* conv_out_b= (const float*)d_in[14];
    const float* wa_kv_w   = (const float*)d_in[15];
    const float* wa_kv_b   = (const float*)d_in[16];
    const float* wa_proj_w = (const float*)d_in[17];
    const float* wa_proj_b = (const float*)d_in[18];
    const float* ln_w      = (const float*)d_in[19];
    const float* ln_b      = (const float*)d_in[20];
    const float* pw1_w     = (const float*)d_in[21];
    const float* pw1_b     = (const float*)d_in[22];
    const float* pw2_w     = (const float*)d_in[23];
    const float* pw2_b     = (const float*)d_in[24];
    const float* gamma     = (const float*)d_in[25];
    float* out = (float*)d_out;

    // Workspace: bf16 pools + fp32 accumulators. Total ~216 MiB.
    bf16* pos = (bf16*)d_ws;                 // 1,572,864 elems
    bf16* P1  = pos + 1572864;               // 25,165,824 elems (50.3 MB)
    bf16* P2  = P1 + 25165824;               // 25,165,824 elems
    bf16* P3  = P2 + 25165824;               // 50,331,648 elems (100.7 MB)
    float* knsq    = (float*)(P3 + 50331648);// 6,144  (xca)
    float* knsq_wa = knsq + 6144;            // 24,576 (wa)
    float* S_xca   = knsq_wa + 24576;        // 64*9216   = 589,824
    float* S_wa    = S_xca + 589824;         // 256*9216  = 2,359,296

    // zero knsq + knsq_wa + S_xca + S_wa = 2,979,840 floats = 11640 * 256
    zero_kernel<<<11640, 256, 0, stream>>>(knsq);

    // pos embedding
    pos_kernel<<<4096, 128, 0, stream>>>(pos_w, pos_b, pos);

    // multi-scale depthwise conv chain -> P1 (xcat)
    dwconv_kernel<<<NBATCH * 96, 256, 0, stream>>>(x,   0, nullptr, 0,  convs_w,        convs_b,       P1, 0);
    dwconv_kernel<<<NBATCH * 96, 256, 0, stream>>>(x,  96, P1,      0,  convs_w + 864,  convs_b + 96,  P1, 96);
    dwconv_kernel<<<NBATCH * 96, 256, 0, stream>>>(x, 192, P1,     96,  convs_w + 1728, convs_b + 192, P1, 192);
    convert_last_kernel<<<6144, 256, 0, stream>>>(x, P1);

    // x3 = transpose(xcat) + pos -> P2
    x3_kernel<<<dim3(12, 128, NBATCH), dim3(32, 8), 0, stream>>>(P1, pos, P2);

    // XCA: LN -> kv -> knorm -> split attention -> proj(+res*gamma_xca) = x4
    ln_kernel<<<NROWS, 128, 0, stream>>>(P2, ln_xca_w, ln_xca_b, P1, 0);
    gemm_kernel<<<dim3(1024, 12), 256, 0, stream>>>(P1, xca_kv_w, xca_kv_b, P3,
                                                    NROWS, 768, 384, 0, nullptr, nullptr);
    knormsq_kernel<<<dim3(16, 16), 384, 0, stream>>>(P3, knsq, 4096, 256);
    chan_qk_kernel<<<512, 256, 0, stream>>>(x, nullptr, P3, knsq, S_xca, 4096, 8, 0);
    chan_softmax_kernel<<<64, 128, 0, stream>>>(S_xca, xca_temp, 0);
    chan_pv_kernel<<<512, 256, 0, stream>>>(S_xca, P3, P1, 4096, 8, 0);
    gemm_kernel<<<dim3(1024, 6), 256, 0, stream>>>(P1, xca_proj_w, xca_proj_b, P3,
                                                   NROWS, 384, 384, 2, P2, gamma_xca);  // x4 -> P3 lo

    // window attention
    unfold_cu_kernel<<<98304, 256, 0, stream>>>(x, P2);                                 // cu_t
    unfold_xu_kernel<<<98304, 256, 0, stream>>>(P3, conv_out_w, conv_out_b, P1);        // xu
    gemm_kernel<<<dim3(1024, 12), 256, 0, stream>>>(P1, wa_kv_w, wa_kv_b, P3,
                                                    NROWS, 768, 384, 0, nullptr, nullptr);
    knormsq_kernel<<<dim3(64, 4), 384, 0, stream>>>(P3, knsq_wa, 1024, 256);
    chan_qk_kernel<<<512, 256, 0, stream>>>(nullptr, P2, P3, knsq_wa, S_wa, 1024, 2, 1);
    chan_softmax_kernel<<<256, 128, 0, stream>>>(S_wa, nullptr, 1);
    chan_pv_kernel<<<512, 256, 0, stream>>>(S_wa, P3, P1, 1024, 2, 1);                  // Xpre
    gemm_kernel<<<dim3(1024, 6), 256, 0, stream>>>(P1, wa_proj_w, wa_proj_b, P2,
                                                   NROWS, 384, 384, 0, nullptr, nullptr);      // Y

    // MLP: LN(fold remap) -> pw1(gelu) -> pw2, chunked 4x16384 rows
    ln_kernel<<<NROWS, 128, 0, stream>>>(P2, ln_w, ln_b, P1, 1);
    for (int ch = 0; ch < 4; ++ch) {
        gemm_kernel<<<dim3(256, 24), 256, 0, stream>>>(P1 + (size_t)ch * 16384 * 384, pw1_w, pw1_b,
                                                       P3, 16384, 1536, 384, 1, nullptr, nullptr);
        gemm_kernel<<<dim3(256, 6), 256, 0, stream>>>(P3, pw2_w, pw2_b,
                                                      P2 + (size_t)ch * 16384 * 384, 16384, 384, 1536,
                                                      0, nullptr, nullptr);
    }

    // out = inp + gamma * final (transpose back to NCHW)
    out_kernel<<<dim3(12, 128, NBATCH), dim3(32, 8), 0, stream>>>(x, P2, gamma, out);
}

// Round 4
// 2596.039 us; speedup vs baseline: 3.2637x; 1.9794x over previous
//
#include <hip/hip_runtime.h>
#include <math.h>

// Problem constants
#define NBATCH 16
#define CDIM   384
#define NPIX   4096      // H*W = 64*64
#define HDCH   96        // channels per head
#define NROWS  65536     // NBATCH*NPIX

typedef unsigned short bf16;
typedef __attribute__((ext_vector_type(8))) short short8;
typedef __attribute__((ext_vector_type(4))) float floatx4;

__device__ __forceinline__ float b2f(bf16 u) {
    union { unsigned int i; float f; } c; c.i = ((unsigned int)u) << 16; return c.f;
}
__device__ __forceinline__ bf16 f2b(float f) {
    union { float f; unsigned int i; } c; c.f = f;
    unsigned int r = (c.i + 0x7FFFu + ((c.i >> 16) & 1u)) >> 16;
    return (bf16)r;
}

// ---------------------------------------------------------------------------
// 0) zero scratch accumulators
// ---------------------------------------------------------------------------
__global__ __launch_bounds__(256) void zero_kernel(float* __restrict__ p) {
    p[blockIdx.x * 256 + threadIdx.x] = 0.0f;
}

// ---------------------------------------------------------------------------
// 1) Fourier positional embedding: pos[n, c] (bf16 out)
// ---------------------------------------------------------------------------
__global__ __launch_bounds__(128) void pos_kernel(const float* __restrict__ pos_w,
                                                  const float* __restrict__ pos_b,
                                                  bf16* __restrict__ pos) {
    __shared__ float feat[64];
    int n = blockIdx.x;
    int yi = n >> 6, xi = n & 63;
    int tid = threadIdx.x;
    if (tid < 64) {
        int j = tid & 31;
        int isx = tid >= 32;
        float base = (float)((isx ? xi : yi) + 1);
        float val = base / (64.0f + 1e-6f) * 6.283185307179586f;
        float e = (float)(2 * (j >> 1)) / 32.0f;
        float dt = powf(10000.0f, e);
        float a = val / dt;
        feat[isx * 32 + j] = (j & 1) ? cosf(a) : sinf(a);
    }
    __syncthreads();
    for (int c = tid; c < CDIM; c += 128) {
        float s = pos_b[c];
        const float* wr = pos_w + c * 64;
        #pragma unroll 16
        for (int j = 0; j < 64; ++j) s += feat[j] * wr[j];
        pos[n * CDIM + c] = f2b(s);
    }
}

// ---------------------------------------------------------------------------
// 2) Depthwise 3x3 conv (pad 1). xin fp32 chunk (+ prev bf16 chunk), out bf16.
// ---------------------------------------------------------------------------
__global__ __launch_bounds__(256) void dwconv_kernel(const float* __restrict__ xin, int in_ch0,
                                                     const bf16* __restrict__ prev, int prev_ch0,
                                                     const float* __restrict__ w,
                                                     const float* __restrict__ bias,
                                                     bf16* __restrict__ out, int out_ch0) {
    __shared__ float tile[66][66];
    int b = blockIdx.x / 96, c = blockIdx.x % 96;
    const float* ip = xin + (b * CDIM + in_ch0 + c) * NPIX;
    const bf16* pp = prev ? prev + (b * CDIM + prev_ch0 + c) * NPIX : nullptr;
    int tid = threadIdx.x;
    for (int i = tid; i < 66 * 66; i += 256) {
        int yy = i / 66 - 1, xx = i % 66 - 1;
        float v = 0.0f;
        if (yy >= 0 && yy < 64 && xx >= 0 && xx < 64) {
            v = ip[yy * 64 + xx];
            if (pp) v += b2f(pp[yy * 64 + xx]);
        }
        tile[i / 66][i % 66] = v;
    }
    __syncthreads();
    float wc[9];
    #pragma unroll
    for (int j = 0; j < 9; ++j) wc[j] = w[c * 9 + j];
    float b0 = bias[c];
    bf16* op = out + (b * CDIM + out_ch0 + c) * NPIX;
    for (int p = tid; p < NPIX; p += 256) {
        int y = p >> 6, x = p & 63;
        float a = b0;
        #pragma unroll
        for (int dy = 0; dy < 3; ++dy)
            #pragma unroll
            for (int dx = 0; dx < 3; ++dx)
                a += tile[y + dy][x + dx] * wc[dy * 3 + dx];
        op[p] = f2b(a);
    }
}

// convert channels [288:384) of x (fp32) into xcat (bf16)
__global__ __launch_bounds__(256) void convert_last_kernel(const float* __restrict__ x,
                                                           bf16* __restrict__ xcat) {
    int idx = blockIdx.x * 256 + threadIdx.x;   // 16*96*4096/4 = 1,572,864 threads
    int b = idx / (96 * 1024);
    int rem = idx % (96 * 1024);
    const float4* src = (const float4*)(x + (b * CDIM + 288) * NPIX);
    float4 v = src[rem];
    ushort4 o;
    o.x = f2b(v.x); o.y = f2b(v.y); o.z = f2b(v.z); o.w = f2b(v.w);
    ((ushort4*)(xcat + (b * CDIM + 288) * NPIX))[rem] = o;
}

// ---------------------------------------------------------------------------
// 3) x3[b,n,c] = xcat[b,c,n] + pos[n,c]   (LDS 32x32 transpose, bf16 io)
// ---------------------------------------------------------------------------
__global__ void x3_kernel(const bf16* __restrict__ xcat, const bf16* __restrict__ pos,
                          bf16* __restrict__ x3) {
    __shared__ float t[32][33];
    int c0 = blockIdx.x * 32, n0 = blockIdx.y * 32, b = blockIdx.z;
    int tx = threadIdx.x, ty = threadIdx.y;
    #pragma unroll
    for (int k = 0; k < 4; ++k) {
        int cl = ty + k * 8;
        t[cl][tx] = b2f(xcat[(b * CDIM + c0 + cl) * NPIX + n0 + tx]);
    }
    __syncthreads();
    #pragma unroll
    for (int k = 0; k < 4; ++k) {
        int nl = ty + k * 8;
        x3[(b * NPIX + n0 + nl) * CDIM + c0 + tx] =
            f2b(t[tx][nl] + b2f(pos[(n0 + nl) * CDIM + c0 + tx]));
    }
}

// ---------------------------------------------------------------------------
// 4) Row LayerNorm over C=384, bf16 io. map=1: fold-remap source row.
// ---------------------------------------------------------------------------
__global__ __launch_bounds__(128) void ln_kernel(const bf16* __restrict__ in,
                                                 const float* __restrict__ w,
                                                 const float* __restrict__ b,
                                                 bf16* __restrict__ out, int map) {
    int r = blockIdx.x;
    int src = r;
    if (map == 1) {
        int bb = r >> 12;
        int p = r & 4095;
        int y = p >> 6, x = p & 63;
        int patch = ((y & 1) << 1) | (x & 1);
        int blk = ((y >> 1) << 5) | (x >> 1);
        src = ((bb << 2) + patch) * 1024 + blk;
    }
    const bf16* row = in + src * CDIM;
    int tid = threadIdx.x;
    float v[3];
    float s1 = 0.0f, s2 = 0.0f;
    #pragma unroll
    for (int i = 0; i < 3; ++i) {
        v[i] = b2f(row[tid + i * 128]);
        s1 += v[i];
        s2 += v[i] * v[i];
    }
    __shared__ float r1[128], r2[128];
    r1[tid] = s1; r2[tid] = s2;
    __syncthreads();
    for (int off = 64; off > 0; off >>= 1) {
        if (tid < off) { r1[tid] += r1[tid + off]; r2[tid] += r2[tid + off]; }
        __syncthreads();
    }
    float mean = r1[0] * (1.0f / 384.0f);
    float var = fmaxf(r2[0] * (1.0f / 384.0f) - mean * mean, 0.0f);
    float rstd = rsqrtf(var + 1e-6f);
    #pragma unroll
    for (int i = 0; i < 3; ++i) {
        int c = tid + i * 128;
        out[r * CDIM + c] = f2b((v[i] - mean) * rstd * w[c] + b[c]);
    }
}

// ---------------------------------------------------------------------------
// 5) MFMA GEMM: C[M,Nout] = epi(A[M,K](bf16) @ W[Nout,K]^T(fp32) + bias)
//    128x128 tile, BK=32, 4 waves, 16x16x32 bf16 MFMA.
//    mode 0: plain   mode 1: exact GELU   mode 2: res(bf16) + scalevec[c]*(.)
// ---------------------------------------------------------------------------
#define LDP 48   // LDS row pad (elems): 96B stride, 16B aligned
__global__ __launch_bounds__(256) void mfma_gemm_kernel(const bf16* __restrict__ A,
                                                        const float* __restrict__ W,
                                                        const float* __restrict__ bias,
                                                        bf16* __restrict__ C,
                                                        int M, int Nout, int K, int mode,
                                                        const bf16* __restrict__ res,
                                                        const float* __restrict__ scalevec) {
    __shared__ bf16 As[128][LDP];
    __shared__ bf16 Bs[128][LDP];
    int m0 = blockIdx.x * 128;
    int n0 = blockIdx.y * 128;
    int tid = threadIdx.x;
    int wave = tid >> 6, lane = tid & 63;
    int wm = (wave & 1) * 64;
    int wn = (wave >> 1) * 64;
    int quad = lane >> 4;
    int lrow = lane & 15;

    int sRow = tid >> 1;          // staging row 0..127
    int sK = (tid & 1) * 16;      // staging k-offset 0 or 16

    floatx4 acc[4][4] = {};

    for (int k0 = 0; k0 < K; k0 += 32) {
        // global loads (A bf16, W fp32 -> cvt)
        const bf16* ap = A + (size_t)(m0 + sRow) * K + k0 + sK;
        short8 a0 = *(const short8*)(ap);
        short8 a1 = *(const short8*)(ap + 8);
        const float* wp = W + (size_t)(n0 + sRow) * K + k0 + sK;
        float4 w0 = *(const float4*)(wp);
        float4 w1 = *(const float4*)(wp + 4);
        float4 w2 = *(const float4*)(wp + 8);
        float4 w3 = *(const float4*)(wp + 12);
        union { short8 v; bf16 u[8]; } p0, p1;
        p0.u[0] = f2b(w0.x); p0.u[1] = f2b(w0.y); p0.u[2] = f2b(w0.z); p0.u[3] = f2b(w0.w);
        p0.u[4] = f2b(w1.x); p0.u[5] = f2b(w1.y); p0.u[6] = f2b(w1.z); p0.u[7] = f2b(w1.w);
        p1.u[0] = f2b(w2.x); p1.u[1] = f2b(w2.y); p1.u[2] = f2b(w2.z); p1.u[3] = f2b(w2.w);
        p1.u[4] = f2b(w3.x); p1.u[5] = f2b(w3.y); p1.u[6] = f2b(w3.z); p1.u[7] = f2b(w3.w);
        __syncthreads();   // previous iter's LDS reads done
        *(short8*)(&As[sRow][sK])     = a0;
        *(short8*)(&As[sRow][sK + 8]) = a1;
        *(short8*)(&Bs[sRow][sK])     = p0.v;
        *(short8*)(&Bs[sRow][sK + 8]) = p1.v;
        __syncthreads();
        short8 af[4], bfr[4];
        #pragma unroll
        for (int i = 0; i < 4; ++i)
            af[i] = *(const short8*)(&As[wm + i * 16 + lrow][quad * 8]);
        #pragma unroll
        for (int j = 0; j < 4; ++j)
            bfr[j] = *(const short8*)(&Bs[wn + j * 16 + lrow][quad * 8]);
        #pragma unroll
        for (int i = 0; i < 4; ++i)
            #pragma unroll
            for (int j = 0; j < 4; ++j)
                acc[i][j] = __builtin_amdgcn_mfma_f32_16x16x32_bf16(af[i], bfr[j], acc[i][j], 0, 0, 0);
    }

    // epilogue: D row = quad*4+reg (within 16-tile), col = lrow
    #pragma unroll
    for (int i = 0; i < 4; ++i) {
        int rowb = m0 + wm + i * 16 + quad * 4;
        #pragma unroll
        for (int j = 0; j < 4; ++j) {
            int col = n0 + wn + j * 16 + lrow;
            float bv = bias[col];
            #pragma unroll
            for (int r = 0; r < 4; ++r) {
                int row = rowb + r;
                float v = acc[i][j][r] + bv;
                if (mode == 1) {
                    v = 0.5f * v * (1.0f + erff(v * 0.70710678118654752f));
                } else if (mode == 2) {
                    v = b2f(res[(size_t)row * Nout + col]) + scalevec[col] * v;
                }
                C[(size_t)row * Nout + col] = f2b(v);
            }
        }
    }
}

// ---------------------------------------------------------------------------
// 6) k column sum-of-squares (over tokens), atomic partials. kv bf16 [rows,768].
// ---------------------------------------------------------------------------
__global__ __launch_bounds__(384) void knormsq_kernel(const bf16* __restrict__ kv,
                                                      float* __restrict__ outk,
                                                      int n_len, int chunk) {
    int bi = blockIdx.x;
    int n0 = blockIdx.y * chunk;
    int ch = threadIdx.x;
    const bf16* base = kv + (size_t)(bi * n_len + n0) * 768 + ch;
    float s = 0.0f;
    for (int t = 0; t < chunk; ++t) {
        float v = b2f(base[(size_t)t * 768]);
        s += v * v;
    }
    atomicAdd(&outk[bi * CDIM + ch], s);
}

// ---------------------------------------------------------------------------
// 7a) S partial accumulate: S[pair, c, d] += sum_{n in chunk} Q[c,n] * Khat[d,n]
// ---------------------------------------------------------------------------
__global__ __launch_bounds__(256) void chan_qk_kernel(const float* __restrict__ qf,
                                                      const bf16* __restrict__ qb,
                                                      const bf16* __restrict__ kv,
                                                      const float* __restrict__ knormsq,
                                                      float* __restrict__ Sg,
                                                      int n_len, int nchunks, int mode) {
    __shared__ float Qt[96][33];
    __shared__ float KVt[96][33];
    __shared__ float knrm[96];
    int pair = blockIdx.x / nchunks, ck = blockIdx.x % nchunks;
    int bi = pair >> 2, h = pair & 3;
    int koff = h * HDCH;
    int chunk = n_len / nchunks;
    int nbeg = ck * chunk, nend = nbeg + chunk;
    const size_t qoff = (size_t)(bi * CDIM + koff) * n_len;
    const bf16* kvb = kv + (size_t)bi * n_len * 768;
    int tid = threadIdx.x;
    if (tid < 96) knrm[tid] = 1.0f / fmaxf(sqrtf(knormsq[bi * CDIM + koff + tid]), 1e-12f);
    __syncthreads();
    int tx = tid & 15, ty = tid >> 4;
    float acc[6][6] = {};
    for (int n0 = nbeg; n0 < nend; n0 += 32) {
        for (int i = tid; i < 96 * 32; i += 256) {
            int c = i >> 5, t = i & 31;
            Qt[c][t] = (mode == 0) ? qf[qoff + (size_t)c * n_len + n0 + t]
                                   : b2f(qb[qoff + (size_t)c * n_len + n0 + t]);
        }
        for (int i = tid; i < 96 * 32; i += 256) {
            int d = i % 96, t = i / 96;
            KVt[d][t] = b2f(kvb[(size_t)(n0 + t) * 768 + koff + d]) * knrm[d];
        }
        __syncthreads();
        #pragma unroll 4
        for (int t = 0; t < 32; ++t) {
            float qr[6], kr[6];
            #pragma unroll
            for (int u = 0; u < 6; ++u) { qr[u] = Qt[ty * 6 + u][t]; kr[u] = KVt[tx * 6 + u][t]; }
            #pragma unroll
            for (int u = 0; u < 6; ++u)
                #pragma unroll
                for (int v = 0; v < 6; ++v)
                    acc[u][v] += qr[u] * kr[v];
        }
        __syncthreads();
    }
    float* Sp = Sg + (size_t)pair * 9216;
    #pragma unroll
    for (int u = 0; u < 6; ++u)
        #pragma unroll
        for (int v = 0; v < 6; ++v)
            atomicAdd(&Sp[(ty * 6 + u) * 96 + tx * 6 + v], acc[u][v]);
}

// ---------------------------------------------------------------------------
// 7b) softmax rows of S. mode 0: softmax(S*temp[h]); mode 1: double softmax.
// ---------------------------------------------------------------------------
__global__ __launch_bounds__(128) void chan_softmax_kernel(float* __restrict__ Sg,
                                                           const float* __restrict__ temp,
                                                           int mode) {
    int pair = blockIdx.x;
    int tid = threadIdx.x;
    if (tid >= 96) return;
    float* Sr = Sg + (size_t)pair * 9216 + tid * 96;
    if (mode == 0) {
        float tv = temp[pair & 3];
        float m = -1e30f;
        for (int d = 0; d < 96; ++d) m = fmaxf(m, Sr[d] * tv);
        float s = 0.0f;
        for (int d = 0; d < 96; ++d) s += expf(Sr[d] * tv - m);
        float inv = 1.0f / s;
        for (int d = 0; d < 96; ++d) Sr[d] = expf(Sr[d] * tv - m) * inv;
    } else {
        const float RSQ = 0.10206207261596575f;  // 1/sqrt(96)
        float m1 = -1e30f;
        for (int d = 0; d < 96; ++d) m1 = fmaxf(m1, Sr[d]);
        float s1 = 0.0f;
        for (int d = 0; d < 96; ++d) s1 += expf(Sr[d] - m1);
        float inv1 = 1.0f / s1;
        float m2 = -1e30f;
        for (int d = 0; d < 96; ++d) {
            float a = 0.5f * Sr[d] * RSQ + 0.5f * expf(Sr[d] - m1) * inv1;
            m2 = fmaxf(m2, a);
        }
        float s2 = 0.0f;
        for (int d = 0; d < 96; ++d) {
            float a = 0.5f * Sr[d] * RSQ + 0.5f * expf(Sr[d] - m1) * inv1;
            s2 += expf(a - m2);
        }
        float inv2 = 1.0f / s2;
        for (int d = 0; d < 96; ++d) {
            float a = 0.5f * Sr[d] * RSQ + 0.5f * expf(Sr[d] - m1) * inv1;
            Sr[d] = expf(a - m2) * inv2;
        }
    }
}

// ---------------------------------------------------------------------------
// 7c) PV: out[c,n] = sum_d attn[c,d] * V[d,n], token-chunked.
// ---------------------------------------------------------------------------
__global__ __launch_bounds__(256) void chan_pv_kernel(const float* __restrict__ Sg,
                                                      const bf16* __restrict__ kv,
                                                      bf16* __restrict__ out,
                                                      int n_len, int nchunks, int mode) {
    __shared__ float Sl[96][97];
    __shared__ float Vt[96][33];
    int pair = blockIdx.x / nchunks, ck = blockIdx.x % nchunks;
    int bi = pair >> 2, h = pair & 3;
    int koff = h * HDCH;
    int chunk = n_len / nchunks;
    int nbeg = ck * chunk, nend = nbeg + chunk;
    const bf16* kvb = kv + (size_t)bi * n_len * 768;
    int tid = threadIdx.x;
    const float* Sp = Sg + (size_t)pair * 9216;
    for (int i = tid; i < 9216; i += 256) Sl[i / 96][i % 96] = Sp[i];
    __syncthreads();
    int tn = tid & 31, tc = tid >> 5;
    for (int n0 = nbeg; n0 < nend; n0 += 32) {
        for (int i = tid; i < 96 * 32; i += 256) {
            int d = i % 96, t = i / 96;
            Vt[d][t] = b2f(kvb[(size_t)(n0 + t) * 768 + 384 + koff + d]);
        }
        __syncthreads();
        #pragma unroll
        for (int j = 0; j < 12; ++j) {
            int c = tc * 12 + j;
            float a = 0.0f;
            #pragma unroll 8
            for (int d = 0; d < 96; ++d) a += Sl[c][d] * Vt[d][tn];
            if (mode == 0)
                out[(size_t)(bi * n_len + n0 + tn) * CDIM + koff + c] = f2b(a);
            else
                out[(size_t)((h * 64 + bi) * HDCH + c) * n_len + n0 + tn] = f2b(a);
        }
        __syncthreads();
    }
}

// ---------------------------------------------------------------------------
// 8) Unfold gathers
// ---------------------------------------------------------------------------
__global__ __launch_bounds__(256) void unfold_cu_kernel(const float* __restrict__ xin,
                                                        bf16* __restrict__ cu) {
    int idx = blockIdx.x * 256 + threadIdx.x;    // 64*384*1024 total
    int b2 = idx / (CDIM * 1024);
    int rem = idx % (CDIM * 1024);
    int ch = rem >> 10, blk = rem & 1023;
    int b = b2 >> 2, patch = b2 & 3;
    int y = ((blk >> 5) << 1) | (patch >> 1);
    int x = ((blk & 31) << 1) | (patch & 1);
    cu[idx] = f2b(xin[(size_t)(b * CDIM + ch) * NPIX + (y << 6) + x]);
}

__global__ __launch_bounds__(256) void unfold_xu_kernel(const bf16* __restrict__ x4,
                                                        const float* __restrict__ cw,
                                                        const float* __restrict__ cb,
                                                        bf16* __restrict__ xu) {
    int idx = blockIdx.x * 256 + threadIdx.x;
    int row = idx / CDIM, ch = idx % CDIM;
    int b2 = row >> 10, blk = row & 1023;
    int b = b2 >> 2, patch = b2 & 3;
    int y = ((blk >> 5) << 1) | (patch >> 1);
    int x = ((blk & 31) << 1) | (patch & 1);
    xu[idx] = f2b(b2f(x4[(size_t)(b * NPIX + (y << 6) + x) * CDIM + ch]) * cw[ch] + cb[ch]);
}

// ---------------------------------------------------------------------------
// 9) out[b,c,p] = inp[b,c,p] + gamma[c] * final[(b*4096+p), c]  (fp32 out)
// ---------------------------------------------------------------------------
__global__ void out_kernel(const float* __restrict__ xin, const bf16* __restrict__ fin,
                           const float* __restrict__ gamma, float* __restrict__ outp) {
    __shared__ float t[32][33];
    int c0 = blockIdx.x * 32, p0 = blockIdx.y * 32, b = blockIdx.z;
    int tx = threadIdx.x, ty = threadIdx.y;
    #pragma unroll
    for (int k = 0; k < 4; ++k) {
        int pl = ty + k * 8;
        t[pl][tx] = b2f(fin[(size_t)(b * NPIX + p0 + pl) * CDIM + c0 + tx]);
    }
    __syncthreads();
    #pragma unroll
    for (int k = 0; k < 4; ++k) {
        int cl = ty + k * 8;
        size_t addr = (size_t)(b * CDIM + c0 + cl) * NPIX + p0 + tx;
        outp[addr] = xin[addr] + gamma[c0 + cl] * t[tx][cl];
    }
}

// ---------------------------------------------------------------------------
extern "C" void kernel_launch(void* const* d_in, const int* in_sizes, int n_in,
                              void* d_out, int out_size, void* d_ws, size_t ws_size,
                              hipStream_t stream) {
    (void)in_sizes; (void)n_in; (void)out_size; (void)ws_size;
    const float* x         = (const float*)d_in[0];
    const float* convs_w   = (const float*)d_in[1];
    const float* convs_b   = (const float*)d_in[2];
    const float* pos_w     = (const float*)d_in[3];
    const float* pos_b     = (const float*)d_in[4];
    const float* ln_xca_w  = (const float*)d_in[5];
    const float* ln_xca_b  = (const float*)d_in[6];
    const float* gamma_xca = (const float*)d_in[7];
    const float* xca_temp  = (const float*)d_in[8];
    const float* xca_kv_w  = (const float*)d_in[9];
    const float* xca_kv_b  = (const float*)d_in[10];
    const float* xca_proj_w= (const float*)d_in[11];
    const float* xca_proj_b= (const float*)d_in[12];
    const float* conv_out_w= (const float*)d_in[13];
    const float* conv_out_b= (const float*)d_in[14];
    const float* wa_kv_w   = (const float*)d_in[15];
    const float* wa_kv_b   = (const float*)d_in[16];
    const float* wa_proj_w = (const float*)d_in[17];
    const float* wa_proj_b = (const float*)d_in[18];
    const float* ln_w      = (const float*)d_in[19];
    const float* ln_b      = (const float*)d_in[20];
    const float* pw1_w     = (const float*)d_in[21];
    const float* pw1_b     = (const float*)d_in[22];
    const float* pw2_w     = (const float*)d_in[23];
    const float* pw2_b     = (const float*)d_in[24];
    const float* gamma     = (const float*)d_in[25];
    float* out = (float*)d_out;

    // Workspace: bf16 pools + fp32 accumulators. Total ~216 MiB.
    bf16* pos = (bf16*)d_ws;                 // 1,572,864 elems
    bf16* P1  = pos + 1572864;               // 25,165,824 elems (50.3 MB)
    bf16* P2  = P1 + 25165824;               // 25,165,824 elems
    bf16* P3  = P2 + 25165824;               // 50,331,648 elems (100.7 MB)
    float* knsq    = (float*)(P3 + 50331648);// 6,144  (xca)
    float* knsq_wa = knsq + 6144;            // 24,576 (wa)
    float* S_xca   = knsq_wa + 24576;        // 64*9216   = 589,824
    float* S_wa    = S_xca + 589824;         // 256*9216  = 2,359,296

    // zero knsq + knsq_wa + S_xca + S_wa = 2,979,840 floats = 11640 * 256
    zero_kernel<<<11640, 256, 0, stream>>>(knsq);

    // pos embedding
    pos_kernel<<<4096, 128, 0, stream>>>(pos_w, pos_b, pos);

    // multi-scale depthwise conv chain -> P1 (xcat)
    dwconv_kernel<<<NBATCH * 96, 256, 0, stream>>>(x,   0, nullptr, 0,  convs_w,        convs_b,       P1, 0);
    dwconv_kernel<<<NBATCH * 96, 256, 0, stream>>>(x,  96, P1,      0,  convs_w + 864,  convs_b + 96,  P1, 96);
    dwconv_kernel<<<NBATCH * 96, 256, 0, stream>>>(x, 192, P1,     96,  convs_w + 1728, convs_b + 192, P1, 192);
    convert_last_kernel<<<6144, 256, 0, stream>>>(x, P1);

    // x3 = transpose(xcat) + pos -> P2
    x3_kernel<<<dim3(12, 128, NBATCH), dim3(32, 8), 0, stream>>>(P1, pos, P2);

    // XCA: LN -> kv -> knorm -> split attention -> proj(+res*gamma_xca) = x4
    ln_kernel<<<NROWS, 128, 0, stream>>>(P2, ln_xca_w, ln_xca_b, P1, 0);
    mfma_gemm_kernel<<<dim3(512, 6), 256, 0, stream>>>(P1, xca_kv_w, xca_kv_b, P3,
                                                       NROWS, 768, 384, 0, nullptr, nullptr);
    knormsq_kernel<<<dim3(16, 16), 384, 0, stream>>>(P3, knsq, 4096, 256);
    chan_qk_kernel<<<512, 256, 0, stream>>>(x, nullptr, P3, knsq, S_xca, 4096, 8, 0);
    chan_softmax_kernel<<<64, 128, 0, stream>>>(S_xca, xca_temp, 0);
    chan_pv_kernel<<<512, 256, 0, stream>>>(S_xca, P3, P1, 4096, 8, 0);
    mfma_gemm_kernel<<<dim3(512, 3), 256, 0, stream>>>(P1, xca_proj_w, xca_proj_b, P3,
                                                       NROWS, 384, 384, 2, P2, gamma_xca);  // x4 -> P3 lo

    // window attention
    unfold_cu_kernel<<<98304, 256, 0, stream>>>(x, P2);                                 // cu_t
    unfold_xu_kernel<<<98304, 256, 0, stream>>>(P3, conv_out_w, conv_out_b, P1);        // xu
    mfma_gemm_kernel<<<dim3(512, 6), 256, 0, stream>>>(P1, wa_kv_w, wa_kv_b, P3,
                                                       NROWS, 768, 384, 0, nullptr, nullptr);
    knormsq_kernel<<<dim3(64, 4), 384, 0, stream>>>(P3, knsq_wa, 1024, 256);
    chan_qk_kernel<<<512, 256, 0, stream>>>(nullptr, P2, P3, knsq_wa, S_wa, 1024, 2, 1);
    chan_softmax_kernel<<<256, 128, 0, stream>>>(S_wa, nullptr, 1);
    chan_pv_kernel<<<512, 256, 0, stream>>>(S_wa, P3, P1, 1024, 2, 1);                  // Xpre
    mfma_gemm_kernel<<<dim3(512, 3), 256, 0, stream>>>(P1, wa_proj_w, wa_proj_b, P2,
                                                       NROWS, 384, 384, 0, nullptr, nullptr);  // Y

    // MLP: LN(fold remap) -> pw1(gelu) -> pw2, chunked 4x16384 rows
    ln_kernel<<<NROWS, 128, 0, stream>>>(P2, ln_w, ln_b, P1, 1);
    for (int ch = 0; ch < 4; ++ch) {
        mfma_gemm_kernel<<<dim3(128, 12), 256, 0, stream>>>(P1 + (size_t)ch * 16384 * 384, pw1_w, pw1_b,
                                                            P3, 16384, 1536, 384, 1, nullptr, nullptr);
        mfma_gemm_kernel<<<dim3(128, 3), 256, 0, stream>>>(P3, pw2_w, pw2_b,
                                                           P2 + (size_t)ch * 16384 * 384, 16384, 384, 1536,
                                                           0, nullptr, nullptr);
    }

    // out = inp + gamma * final (transpose back to NCHW)
    out_kernel<<<dim3(12, 128, NBATCH), dim3(32, 8), 0, stream>>>(x, P2, gamma, out);
}